// Round 7
// baseline (370.618 us; speedup 1.0000x reference)
//
#include <hip/hip_runtime.h>

// CRF forward partition, MI355X. B=1024, L=512, T=52 (padded to 64).
//
// R7: MFMA-batched reformulation. Per wave: 16 batches. Per step t:
//   Q_new(64 tags x 16 batches) = E^T(64x64) . Q(64x16), then *= exp(f),
//   mask-select, renorm every 4 steps.
// E^T constant -> preloaded A-frags (bf16). Q state round-trips through a
// bf16 LDS buffer laid out in B-fragment order so ds_read_b128 yields the
// packed B operands directly. C/D layout (m89): row=quad*4+reg, col=lane&15.
// A/B layouts (m120): A[m=lane&15][k=quad*8+jj], B[k=quad*8+jj][n=lane&15].
//
// Evidence R2-R6: readlane broadcast is the wall (~8cyc/readlane => ~640
// cyc/step/batch); MFMA does 16 batches' matvec in 8 instructions.

#define TT 52
#define LL 512
#define BT 16   // batches per wave

typedef __attribute__((ext_vector_type(8))) short s16x8;
typedef __attribute__((ext_vector_type(4))) short s16x4;
typedef __attribute__((ext_vector_type(4))) float f32x4;

__device__ __forceinline__ float bperm_f(int srclane, float v) {
    return __int_as_float(__builtin_amdgcn_ds_bpermute(srclane * 4, __float_as_int(v)));
}
__device__ __forceinline__ short f2bf(float f) {   // RNE f32 -> bf16 bits
    unsigned u = __float_as_uint(f);
    u = (u + 0x7FFFu + ((u >> 16) & 1u)) >> 16;
    return (short)u;
}

__global__ void __launch_bounds__(64)
__attribute__((amdgpu_waves_per_eu(1, 1)))
crf_fwd(const float* __restrict__ feats, const int* __restrict__ mask,
        const float* __restrict__ trans, float* __restrict__ out)
{
    // bf16 Q in B-frag order: block X = kb*4+q holds tags [X*8, X*8+8) for
    // 16 batches: lq[X*128 + c*8 + jj]
    __shared__ short lq[8 * 128];

    const int lane = threadIdx.x;
    const int c = lane & 15;          // batch col (B/D) / A row m
    const int q = lane >> 4;          // quad
    const int b0 = blockIdx.x * BT;

    const float* fb = feats + (size_t)(b0 + c) * LL * TT;
    const int*   mb = mask  + (size_t)(b0 + c) * LL;

    // per-lane feats tile tag bases; tile 3 q>0 are pad tags (>=52):
    // clamp address to 48 (valid, junk); their D rows are 0 via A-pad.
    int tb[4];
#pragma unroll
    for (int tt = 0; tt < 4; ++tt)
        tb[tt] = tt * 16 + ((tt == 3 && q > 0) ? 0 : q * 4);

    // LDS write offsets: pv tile tt (tags g=tt*16+q*4+r) -> block
    // X=(tt>>1)*4+((2*tt+(q>>1))&3), jj0=(q&1)*4  (verified bijection)
    int woff[4];
#pragma unroll
    for (int tt = 0; tt < 4; ++tt) {
        int X = (tt >> 1) * 4 + ((2 * tt + (q >> 1)) & 3);
        woff[tt] = X * 128 + c * 8 + (q & 1) * 4;
    }
    const int roff0 = (0 * 4 + q) * 128 + c * 8;   // B-frag kb=0
    const int roff1 = (1 * 4 + q) * 128 + c * 8;   // B-frag kb=1

    // ---- A fragments (constant): A[jt][kb][jj] = E^T[jt*16+c][kb*32+q*8+jj]
    //      = exp(trans[i][j]), i=kb*32+q*8+jj, j=jt*16+c; 0 outside 52x52.
    s16x8 A[4][2];
#pragma unroll
    for (int jt = 0; jt < 4; ++jt)
#pragma unroll
        for (int kb = 0; kb < 2; ++kb)
#pragma unroll
            for (int jj = 0; jj < 8; ++jj) {
                int i = kb * 32 + q * 8 + jj;
                int j = jt * 16 + c;
                int ii = i < TT ? i : TT - 1;
                int jc2 = j < TT ? j : TT - 1;
                float e = __expf(trans[ii * TT + jc2]);
                A[jt][kb][jj] = (i < TT && j < TT) ? f2bf(e) : (short)0;
            }

    // ---- eend[tag] = exp(trans[tag][END]) in C/D layout (epilogue)
    f32x4 eend[4];
#pragma unroll
    for (int tt = 0; tt < 4; ++tt)
#pragma unroll
        for (int r = 0; r < 4; ++r) {
            int g = tt * 16 + q * 4 + r;
            int gc = g < TT ? g : TT - 1;
            float e = __expf(trans[gc * TT + (TT - 1)]);
            eend[tt][r] = (g < TT) ? e : 0.0f;
        }

    // ---- init t=0: pv[tt][r] = exp(f0 + trans[START][tag] - shift)
    float shift;
    f32x4 pv[4];
    {
        f32x4 f0[4], ts[4];
#pragma unroll
        for (int tt = 0; tt < 4; ++tt) {
            f0[tt] = *(const f32x4*)(fb + tb[tt]);
            ts[tt] = *(const f32x4*)(trans + (TT - 2) * TT + tb[tt]);
        }
        float p00 = f0[0][0] + ts[0][0];
        shift = bperm_f(c, p00);          // tag0 part0 of batch c (lane c, q=0)
#pragma unroll
        for (int tt = 0; tt < 4; ++tt) {
            float pm = (tt == 3 && q > 0) ? 0.0f : 1.0f;  // zero pad tags
#pragma unroll
            for (int r = 0; r < 4; ++r)
                pv[tt][r] = pm * __expf(f0[tt][r] + ts[tt][r] - shift);
        }
    }

    // ---- feats/mask prefetch ring (4 steps)
    f32x4 fpre[4][4];
    int   mpre[4];
#pragma unroll
    for (int u = 0; u < 4; ++u) {
        int t = 1 + u;
#pragma unroll
        for (int tt = 0; tt < 4; ++tt)
            fpre[u][tt] = *(const f32x4*)(fb + (size_t)t * TT + tb[tt]);
        mpre[u] = mb[t];
    }

    // ---- main loop: groups of 4, t = 1..508; tail 509..511
    for (int t0 = 1; t0 <= LL - 7; t0 += 4) {
        f32x4 fnx[4][4];
        int   mn[4];
#pragma unroll
        for (int u = 0; u < 4; ++u) {
            int tn = t0 + 4 + u;
            tn = tn < LL ? tn : LL - 1;
#pragma unroll
            for (int tt = 0; tt < 4; ++tt)
                fnx[u][tt] = *(const f32x4*)(fb + (size_t)tn * TT + tb[tt]);
            mn[u] = mb[tn];
        }

#pragma unroll
        for (int u = 0; u < 4; ++u) {
            // publish Q as bf16 in B-frag order
#pragma unroll
            for (int tt = 0; tt < 4; ++tt) {
                s16x4 w;
#pragma unroll
                for (int r = 0; r < 4; ++r) w[r] = f2bf(pv[tt][r]);
                *(s16x4*)&lq[woff[tt]] = w;
            }
            s16x8 B0 = *(s16x8*)&lq[roff0];
            s16x8 B1 = *(s16x8*)&lq[roff1];

            int m = mpre[u];
#pragma unroll
            for (int tt = 0; tt < 4; ++tt) {
                f32x4 D = {0.0f, 0.0f, 0.0f, 0.0f};
                D = __builtin_amdgcn_mfma_f32_16x16x32_bf16(A[tt][0], B0, D, 0, 0, 0);
                D = __builtin_amdgcn_mfma_f32_16x16x32_bf16(A[tt][1], B1, D, 0, 0, 0);
#pragma unroll
                for (int r = 0; r < 4; ++r) {
                    float pn = D[r] * __expf(fpre[u][tt][r]);
                    pv[tt][r] = (m > 0) ? pn : pv[tt][r];
                }
            }
            if (u == 3) {   // renorm by tag0 (always > 0) every 4 steps
                float c0 = bperm_f(c, pv[0][0]);
                shift += __logf(c0);
                float ic = __builtin_amdgcn_rcpf(c0);
#pragma unroll
                for (int tt = 0; tt < 4; ++tt) pv[tt] *= ic;
            }
        }
#pragma unroll
        for (int u = 0; u < 4; ++u) {
#pragma unroll
            for (int tt = 0; tt < 4; ++tt) fpre[u][tt] = fnx[u][tt];
            mpre[u] = mn[u];
        }
    }

    // tail: t = 509,510,511
#pragma unroll
    for (int u = 0; u < 3; ++u) {
#pragma unroll
        for (int tt = 0; tt < 4; ++tt) {
            s16x4 w;
#pragma unroll
            for (int r = 0; r < 4; ++r) w[r] = f2bf(pv[tt][r]);
            *(s16x4*)&lq[woff[tt]] = w;
        }
        s16x8 B0 = *(s16x8*)&lq[roff0];
        s16x8 B1 = *(s16x8*)&lq[roff1];
        int m = mpre[u];
#pragma unroll
        for (int tt = 0; tt < 4; ++tt) {
            f32x4 D = {0.0f, 0.0f, 0.0f, 0.0f};
            D = __builtin_amdgcn_mfma_f32_16x16x32_bf16(A[tt][0], B0, D, 0, 0, 0);
            D = __builtin_amdgcn_mfma_f32_16x16x32_bf16(A[tt][1], B1, D, 0, 0, 0);
#pragma unroll
            for (int r = 0; r < 4; ++r) {
                float pn = D[r] * __expf(fpre[u][tt][r]);
                pv[tt][r] = (m > 0) ? pn : pv[tt][r];
            }
        }
    }

    // ---- epilogue: res_b = log(sum_tag eend*pv) + shift; out += sum_b res_b
    float val = 0.0f;
#pragma unroll
    for (int tt = 0; tt < 4; ++tt)
#pragma unroll
        for (int r = 0; r < 4; ++r)
            val = fmaf(eend[tt][r], pv[tt][r], val);
    val += __shfl_xor(val, 16);
    val += __shfl_xor(val, 32);           // all lanes: full sum for batch c
    float res = __logf(val) + shift;
    float contrib = (q == 0) ? res : 0.0f;
#pragma unroll
    for (int o = 1; o <= 32; o <<= 1)
        contrib += __shfl_xor(contrib, o);
    if (lane == 0) atomicAdd(out, contrib);
}

extern "C" void kernel_launch(void* const* d_in, const int* in_sizes, int n_in,
                              void* d_out, int out_size, void* d_ws, size_t ws_size,
                              hipStream_t stream) {
    const float* feats = (const float*)d_in[0];
    const int*   mask  = (const int*)d_in[1];
    const float* trans = (const float*)d_in[2];
    float* out = (float*)d_out;

    const int B = in_sizes[1] / LL;   // mask is (B, L)

    hipMemsetAsync(d_out, 0, sizeof(float), stream);
    crf_fwd<<<B / BT, 64, 0, stream>>>(feats, mask, trans, out);
}